// Round 1
// baseline (1018.760 us; speedup 1.0000x reference)
//
#include <hip/hip_runtime.h>

#define FD 64  // feature dim

// feats[0:na+nb) = concat(a,b); acc_a[0:na) = a; acc_b[0:nb) = b  (all rows x 64)
__global__ void init_concat_kernel(const float* __restrict__ a, const float* __restrict__ b,
                                   int na, int nb,
                                   float* __restrict__ feats,
                                   float* __restrict__ acc_a, float* __restrict__ acc_b) {
    long long idx = (long long)blockIdx.x * blockDim.x + threadIdx.x;
    long long total = (long long)(na + nb) * FD;
    if (idx >= total) return;
    int row = (int)(idx >> 6);
    float v;
    if (row < na) {
        v = a[idx];
        acc_a[idx] = v;
    } else {
        long long j = idx - (long long)na * FD;
        v = b[j];
        acc_b[j] = v;
    }
    feats[idx] = v;
}

// y[rows[e]] += (vals[e]*scale) * x[cols[e]]  -- one wave per edge, lane = feature dim
__global__ void spmm_atomic_kernel(const int* __restrict__ rows, const int* __restrict__ cols,
                                   const float* __restrict__ vals, const float* __restrict__ x,
                                   float* __restrict__ y, int nnz, float scale) {
    long long t = (long long)blockIdx.x * blockDim.x + threadIdx.x;
    int e = (int)(t >> 6);
    if (e >= nnz) return;
    int d = (int)(t & 63);
    int r = rows[e];
    int c = cols[e];
    float v = vals[e] * scale;
    atomicAdd(&y[(long long)r * FD + d], v * x[(long long)c * FD + d]);
}

// per row: nrm = max(||f_row||_2, 1e-12); acc_row += f_row / nrm
// acc rows [0,split) -> acc_a, rows [split,n) -> acc_b (re-based)
__global__ void norm_add_kernel(const float* __restrict__ f,
                                float* __restrict__ acc_a, float* __restrict__ acc_b,
                                int split, int n) {
    int wave = (int)(((long long)blockIdx.x * blockDim.x + threadIdx.x) >> 6);
    if (wave >= n) return;
    int lane = threadIdx.x & 63;
    float v = f[(long long)wave * FD + lane];
    float s = v * v;
#pragma unroll
    for (int o = 32; o >= 1; o >>= 1) s += __shfl_xor(s, o);
    float nrm = fmaxf(sqrtf(s), 1e-12f);
    float add = v / nrm;
    if (wave < split)
        acc_a[(long long)wave * FD + lane] += add;
    else
        acc_b[(long long)(wave - split) * FD + lane] += add;
}

static inline long long cdiv_ll(long long a, long long b) { return (a + b - 1) / b; }

extern "C" void kernel_launch(void* const* d_in, const int* in_sizes, int n_in,
                              void* d_out, int out_size, void* d_ws, size_t ws_size,
                              hipStream_t stream) {
    const float* users   = (const float*)d_in[0];
    const float* items   = (const float*)d_in[1];
    const float* bundles = (const float*)d_in[2];
    const int*   il_rows = (const int*)d_in[3];
    const int*   il_cols = (const int*)d_in[4];
    const float* il_vals = (const float*)d_in[5];
    const int*   bl_rows = (const int*)d_in[6];
    const int*   bl_cols = (const int*)d_in[7];
    const float* bl_vals = (const float*)d_in[8];
    const int*   bi_rows = (const int*)d_in[9];
    const int*   bi_cols = (const int*)d_in[10];
    const float* bi_vals = (const float*)d_in[11];

    const int U = in_sizes[0] / FD;   // 50000
    const int I = in_sizes[1] / FD;   // 40000
    const int B = in_sizes[2] / FD;   // 20000
    const int nnz_il = in_sizes[3];   // 1,000,000
    const int nnz_bl = in_sizes[6];   //   600,000
    const int nnz_bi = in_sizes[9];   //   500,000
    const int n1 = U + I;             // 90000
    const int n2 = U + B;             // 70000

    float* out = (float*)d_out;
    // output layout: [il_users (U) | bl_users (U) | il_bundles (B) | bl_bundles (B)] x 64
    float* il_users_acc   = out;
    float* bl_users_acc   = out + (size_t)U * FD;
    float* il_bundles_out = out + (size_t)2 * U * FD;
    float* bl_bundles_acc = out + ((size_t)2 * U + B) * FD;

    // workspace: ping (n1 rows) | pong (n1 rows) | items_acc (I rows)
    float* ping      = (float*)d_ws;
    float* pong      = ping + (size_t)n1 * FD;
    float* items_acc = pong + (size_t)n1 * FD;

    const dim3 blk(256);
    const float h = 0.5f, th = 1.0f / 3.0f;

    // ---------------- item-level propagation (users + items, il graph) ------------
    init_concat_kernel<<<(int)cdiv_ll((long long)n1 * FD, 256), blk, 0, stream>>>(
        users, items, U, I, ping, il_users_acc, items_acc);

    hipMemsetAsync(pong, 0, (size_t)n1 * FD * sizeof(float), stream);
    spmm_atomic_kernel<<<(int)cdiv_ll((long long)nnz_il * FD, 256), blk, 0, stream>>>(
        il_rows, il_cols, il_vals, ping, pong, nnz_il, h);
    norm_add_kernel<<<(int)cdiv_ll((long long)n1 * FD, 256), blk, 0, stream>>>(
        pong, il_users_acc, items_acc, U, n1);

    hipMemsetAsync(ping, 0, (size_t)n1 * FD * sizeof(float), stream);
    spmm_atomic_kernel<<<(int)cdiv_ll((long long)nnz_il * FD, 256), blk, 0, stream>>>(
        il_rows, il_cols, il_vals, pong, ping, nnz_il, th);
    norm_add_kernel<<<(int)cdiv_ll((long long)n1 * FD, 256), blk, 0, stream>>>(
        ping, il_users_acc, items_acc, U, n1);

    // bundle aggregation: il_bundles = BI @ il_items_acc
    hipMemsetAsync(il_bundles_out, 0, (size_t)B * FD * sizeof(float), stream);
    spmm_atomic_kernel<<<(int)cdiv_ll((long long)nnz_bi * FD, 256), blk, 0, stream>>>(
        bi_rows, bi_cols, bi_vals, items_acc, il_bundles_out, nnz_bi, 1.0f);

    // ---------------- bundle-level propagation (users + bundles, bl graph) --------
    init_concat_kernel<<<(int)cdiv_ll((long long)n2 * FD, 256), blk, 0, stream>>>(
        users, bundles, U, B, ping, bl_users_acc, bl_bundles_acc);

    hipMemsetAsync(pong, 0, (size_t)n2 * FD * sizeof(float), stream);
    spmm_atomic_kernel<<<(int)cdiv_ll((long long)nnz_bl * FD, 256), blk, 0, stream>>>(
        bl_rows, bl_cols, bl_vals, ping, pong, nnz_bl, h);
    norm_add_kernel<<<(int)cdiv_ll((long long)n2 * FD, 256), blk, 0, stream>>>(
        pong, bl_users_acc, bl_bundles_acc, U, n2);

    hipMemsetAsync(ping, 0, (size_t)n2 * FD * sizeof(float), stream);
    spmm_atomic_kernel<<<(int)cdiv_ll((long long)nnz_bl * FD, 256), blk, 0, stream>>>(
        bl_rows, bl_cols, bl_vals, pong, ping, nnz_bl, th);
    norm_add_kernel<<<(int)cdiv_ll((long long)n2 * FD, 256), blk, 0, stream>>>(
        ping, bl_users_acc, bl_bundles_acc, U, n2);
}